// Round 2
// baseline (167.797 us; speedup 1.0000x reference)
//
#include <hip/hip_runtime.h>

// SFC model forward:
//   out[b] = bias_w[zero[b],0] + dot(user_w[user[b]], item_w[item[b]]) + freq_w[idx_emb[b], freq[b], 0]
// B = 2,097,152, EMB_DIM = 64.
// 16 lanes per sample (lane loads float4 -> 256B coalesced row read).
// Manual 4x unroll of the grid-stride loop: batch index loads, then issue all
// 8 float4 gathers before any reduce -> 4x memory-level parallelism to hide
// ~900-cycle random HBM gather latency (round-1 rocprof: 2.7 TB/s, latency-bound).

#define EMB_DIM 64

__global__ __launch_bounds__(256) void sfc_fwd(
    const int* __restrict__ user, const int* __restrict__ item,
    const int* __restrict__ freq, const int* __restrict__ idx_emb,
    const int* __restrict__ zero, const float* __restrict__ bias_w,
    const float* __restrict__ user_w, const float* __restrict__ item_w,
    const float* __restrict__ freq_w, float* __restrict__ out, int B)
{
    const int group_in_block = threadIdx.x >> 4;   // 16 groups of 16 lanes per 256-thread block
    const int lane = threadIdx.x & 15;
    const int stride = (gridDim.x * blockDim.x) >> 4;
    const int start = blockIdx.x * 16 + group_in_block;

    int s = start;
    for (; s + 3 * stride < B; s += 4 * stride) {
        const int sa = s, sb = s + stride, sc = s + 2 * stride, sd = s + 3 * stride;

        // batch the index loads (independent)
        const int ua = user[sa], ub = user[sb], uc = user[sc], ud = user[sd];
        const int ia = item[sa], ib = item[sb], ic = item[sc], id_ = item[sd];

        // issue all 8 row gathers before consuming any (8 x float4 in flight / lane)
        const float4 uva = *reinterpret_cast<const float4*>(user_w + (size_t)ua * EMB_DIM + lane * 4);
        const float4 uvb = *reinterpret_cast<const float4*>(user_w + (size_t)ub * EMB_DIM + lane * 4);
        const float4 uvc = *reinterpret_cast<const float4*>(user_w + (size_t)uc * EMB_DIM + lane * 4);
        const float4 uvd = *reinterpret_cast<const float4*>(user_w + (size_t)ud * EMB_DIM + lane * 4);
        const float4 iva = *reinterpret_cast<const float4*>(item_w + (size_t)ia * EMB_DIM + lane * 4);
        const float4 ivb = *reinterpret_cast<const float4*>(item_w + (size_t)ib * EMB_DIM + lane * 4);
        const float4 ivc = *reinterpret_cast<const float4*>(item_w + (size_t)ic * EMB_DIM + lane * 4);
        const float4 ivd = *reinterpret_cast<const float4*>(item_w + (size_t)id_ * EMB_DIM + lane * 4);

        float da = uva.x * iva.x + uva.y * iva.y + uva.z * iva.z + uva.w * iva.w;
        float db = uvb.x * ivb.x + uvb.y * ivb.y + uvb.z * ivb.z + uvb.w * ivb.w;
        float dc = uvc.x * ivc.x + uvc.y * ivc.y + uvc.z * ivc.z + uvc.w * ivc.w;
        float dd = uvd.x * ivd.x + uvd.y * ivd.y + uvd.z * ivd.z + uvd.w * ivd.w;

        da += __shfl_xor(da, 1); da += __shfl_xor(da, 2); da += __shfl_xor(da, 4); da += __shfl_xor(da, 8);
        db += __shfl_xor(db, 1); db += __shfl_xor(db, 2); db += __shfl_xor(db, 4); db += __shfl_xor(db, 8);
        dc += __shfl_xor(dc, 1); dc += __shfl_xor(dc, 2); dc += __shfl_xor(dc, 4); dc += __shfl_xor(dc, 8);
        dd += __shfl_xor(dd, 1); dd += __shfl_xor(dd, 2); dd += __shfl_xor(dd, 4); dd += __shfl_xor(dd, 8);

        if (lane == 0) {
            const float bias_a = bias_w[zero[sa]];
            const float bias_b = bias_w[zero[sb]];
            const float bias_c = bias_w[zero[sc]];
            const float bias_d = bias_w[zero[sd]];
            const float fea = freq_w[idx_emb[sa] * 32 + freq[sa]];
            const float feb = freq_w[idx_emb[sb] * 32 + freq[sb]];
            const float fec = freq_w[idx_emb[sc] * 32 + freq[sc]];
            const float fed = freq_w[idx_emb[sd] * 32 + freq[sd]];
            out[sa] = bias_a + da + fea;
            out[sb] = bias_b + db + feb;
            out[sc] = bias_c + dc + fec;
            out[sd] = bias_d + dd + fed;
        }
    }
    // tail (not taken for B = 2M with 2048x256 launch, kept for generality)
    for (; s < B; s += stride) {
        const int u_idx = user[s];
        const int i_idx = item[s];
        const float4 uv = *reinterpret_cast<const float4*>(user_w + (size_t)u_idx * EMB_DIM + lane * 4);
        const float4 vv = *reinterpret_cast<const float4*>(item_w + (size_t)i_idx * EMB_DIM + lane * 4);
        float d = uv.x * vv.x + uv.y * vv.y + uv.z * vv.z + uv.w * vv.w;
        d += __shfl_xor(d, 1); d += __shfl_xor(d, 2); d += __shfl_xor(d, 4); d += __shfl_xor(d, 8);
        if (lane == 0) {
            out[s] = bias_w[zero[s]] + d + freq_w[idx_emb[s] * 32 + freq[s]];
        }
    }
}

extern "C" void kernel_launch(void* const* d_in, const int* in_sizes, int n_in,
                              void* d_out, int out_size, void* d_ws, size_t ws_size,
                              hipStream_t stream) {
    const int B = in_sizes[0];
    const int*   user    = (const int*)d_in[0];
    const int*   item    = (const int*)d_in[1];
    const int*   freq    = (const int*)d_in[2];
    const int*   idx_emb = (const int*)d_in[3];
    const int*   zero    = (const int*)d_in[4];
    const float* bias_w  = (const float*)d_in[5];
    const float* user_w  = (const float*)d_in[6];
    const float* item_w  = (const float*)d_in[7];
    const float* freq_w  = (const float*)d_in[8];
    float* out = (float*)d_out;

    // 2048 blocks x 256 threads = 32 waves/CU (full occupancy), 32768 groups,
    // each group does 64 samples -> 16 unrolled passes.
    const int blocks = 2048;
    sfc_fwd<<<blocks, 256, 0, stream>>>(user, item, freq, idx_emb, zero,
                                        bias_w, user_w, item_w, freq_w, out, B);
}